// Round 5
// baseline (131.460 us; speedup 1.0000x reference)
//
#include <hip/hip_runtime.h>

// Problem dims (fixed by reference setup_inputs)
#define B_  4
#define C_  3
#define S_  5
#define M_  18
#define HW4 11264             // 256*176/4 float4s per plane/channel
#define G_  6                 // m-planes per block, one per wave
#define NGI (S_*M_/G_)        // 15 wave-groups per batch
#define SPLIT 22              // chunks per plane
#define CHUNK4 (HW4/SPLIT)    // 512 float4s per chunk
#define ITERS (CHUNK4/64)     // 8 iterations per wave
#define TPB (G_*64)           // 384 threads = 6 waves
#define NPLANE (B_*S_*M_)     // 360
#define NBLK (B_*NGI*SPLIT)   // 1320 blocks -> 31 waves/CU supplied

// Kernel A: block = (b, s, m-group, chunk). The 6 rescaled X/Y channel
// streams are staged into a double-buffered LDS tile ONCE per block
// (3.4x fewer VMEM requests than per-wave loads; rescale done once).
// Wave w accumulates the 16 raw weighted moments of plane m-group+w.
// bid%4 == b  =>  each XCD's L2 holds only one batch's X/Y (4.3 MB ~ L2).
// Partial layout per (plane,chunk): [0]=msum, [1+c*5+{wx,wy,wxx,wyy,wxy}]
__global__ __launch_bounds__(TPB) void moments_kernel(
    const float4* __restrict__ X, const float4* __restrict__ Y,
    const float4* __restrict__ Mk, float* __restrict__ part) {
  __shared__ float4 tile[2][6][64];   // 12.3 KB

  int bid   = blockIdx.x;            // [0, NBLK)
  int chunk = bid / (B_ * NGI);      // [0, SPLIT)
  int r     = bid - chunk * (B_ * NGI);
  int b     = r & 3;                 // bid%4 == b  (B_*NGI = 60 ≡ 0 mod 4)
  int gi    = r >> 2;                // [0, NGI)
  int s     = gi / 3;
  int mg    = gi - s * 3;            // which group of G_ m-planes
  int wv    = threadIdx.x >> 6;
  int lane  = threadIdx.x & 63;
  int plane = (b * S_ + s) * M_ + mg * G_ + wv;

  const float4* mp = Mk + (size_t)plane * HW4;
  // staging stream for this thread's wave: wv<3 -> X channel wv, else Y channel wv-3
  const float4* sp = (wv < 3) ? (X + (size_t)b * (C_ * HW4) + (size_t)wv * HW4)
                              : (Y + (size_t)b * (C_ * HW4) + (size_t)(wv - 3) * HW4);
  int base = chunk * CHUNK4;

  float v[16];
#pragma unroll
  for (int j = 0; j < 16; ++j) v[j] = 0.f;

  // prologue: stage iteration 0 into buffer 0 (rescale [-1,1]->[0,1] here, once)
  {
    float4 sv = sp[base + lane];
    sv.x = fmaf(sv.x, 0.5f, 0.5f); sv.y = fmaf(sv.y, 0.5f, 0.5f);
    sv.z = fmaf(sv.z, 0.5f, 0.5f); sv.w = fmaf(sv.w, 0.5f, 0.5f);
    tile[0][wv][lane] = sv;
  }

#pragma unroll
  for (int it = 0; it < ITERS; ++it) {
    int buf = it & 1;
    int i   = base + it * 64 + lane;
    float4 w = mp[i];                       // HBM stream — issue before barrier

    __syncthreads();                        // tile[buf] written; old reads drained

    if (it + 1 < ITERS) {                   // stage next into the other buffer
      float4 sv = sp[i + 64];
      sv.x = fmaf(sv.x, 0.5f, 0.5f); sv.y = fmaf(sv.y, 0.5f, 0.5f);
      sv.z = fmaf(sv.z, 0.5f, 0.5f); sv.w = fmaf(sv.w, 0.5f, 0.5f);
      tile[buf ^ 1][wv][lane] = sv;
    }

    float4 xs4[C_], ys4[C_];
#pragma unroll
    for (int c = 0; c < C_; ++c) { xs4[c] = tile[buf][c][lane]; ys4[c] = tile[buf][3 + c][lane]; }

    float w4[4]     = { w.x, w.y, w.z, w.w };
    float xsv[C_][4] = { {xs4[0].x, xs4[0].y, xs4[0].z, xs4[0].w},
                         {xs4[1].x, xs4[1].y, xs4[1].z, xs4[1].w},
                         {xs4[2].x, xs4[2].y, xs4[2].z, xs4[2].w} };
    float ysv[C_][4] = { {ys4[0].x, ys4[0].y, ys4[0].z, ys4[0].w},
                         {ys4[1].x, ys4[1].y, ys4[1].z, ys4[1].w},
                         {ys4[2].x, ys4[2].y, ys4[2].z, ys4[2].w} };
#pragma unroll
    for (int k = 0; k < 4; ++k) {
      float wk = w4[k];
      v[0] += wk;
#pragma unroll
      for (int c = 0; c < C_; ++c) {
        float xs = xsv[c][k], ys = ysv[c][k];
        float wx = wk * xs, wy = wk * ys;
        v[1 + c*5 + 0] = fmaf(wk, xs, v[1 + c*5 + 0]);
        v[1 + c*5 + 1] = fmaf(wk, ys, v[1 + c*5 + 1]);
        v[1 + c*5 + 2] = fmaf(wx, xs, v[1 + c*5 + 2]);
        v[1 + c*5 + 3] = fmaf(wy, ys, v[1 + c*5 + 3]);
        v[1 + c*5 + 4] = fmaf(wx, ys, v[1 + c*5 + 4]);
      }
    }
  }

  // wave-64 butterfly over the 16 per-plane values (no cross-wave reduce)
#pragma unroll
  for (int off = 32; off > 0; off >>= 1) {
#pragma unroll
    for (int j = 0; j < 16; ++j) v[j] += __shfl_xor(v[j], off);
  }

  if (lane == 0) {
    float4* dst = (float4*)(part + (size_t)(plane * SPLIT + chunk) * 16);
    dst[0] = make_float4(v[0],  v[1],  v[2],  v[3]);
    dst[1] = make_float4(v[4],  v[5],  v[6],  v[7]);
    dst[2] = make_float4(v[8],  v[9],  v[10], v[11]);
    dst[3] = make_float4(v[12], v[13], v[14], v[15]);
  }
}

// Kernel B: tiny epilogue. One block.
__global__ __launch_bounds__(384) void finalize_kernel(
    const float* __restrict__ part, float* __restrict__ out) {
  __shared__ float csS[NPLANE], ssS[NPLANE];
  __shared__ double csb[B_*S_], ssb[B_*S_];
  int t = threadIdx.x;

  if (t < NPLANE) {
    double s[16];
#pragma unroll
    for (int j = 0; j < 16; ++j) s[j] = 0.0;
    for (int ch = 0; ch < SPLIT; ++ch) {
      const float4* p = (const float4*)(part + (size_t)(t * SPLIT + ch) * 16);
      float4 q0 = p[0], q1 = p[1], q2 = p[2], q3 = p[3];
      s[0]+=q0.x;  s[1]+=q0.y;  s[2]+=q0.z;  s[3]+=q0.w;
      s[4]+=q1.x;  s[5]+=q1.y;  s[6]+=q1.z;  s[7]+=q1.w;
      s[8]+=q2.x;  s[9]+=q2.y;  s[10]+=q2.z; s[11]+=q2.w;
      s[12]+=q3.x; s[13]+=q3.y; s[14]+=q3.z; s[15]+=q3.w;
    }
    const double C1d = 1e-4, C2d = 9e-4;
    double inv = 1.0 / (s[0] + 1e-6);
    double csAcc = 0.0, ssAcc = 0.0;
#pragma unroll
    for (int c = 0; c < C_; ++c) {
      double mu1  = s[1 + c*5 + 0] * inv;
      double mu2  = s[1 + c*5 + 1] * inv;
      double mu11 = s[1 + c*5 + 2] * inv;
      double mu22 = s[1 + c*5 + 3] * inv;
      double mu12 = s[1 + c*5 + 4] * inv;
      double m1s = mu1*mu1, m2s = mu2*mu2, m12 = mu1*mu2;
      double sig1  = mu11 - m1s;
      double sig2  = mu22 - m2s;
      double sig12 = mu12 - m12;
      double cs   = (2.0*sig12 + C2d) / (sig1 + sig2 + C2d);
      double ssim = (2.0*m12 + C1d) / (m1s + m2s + C1d) * cs;
      if (cs   < 0.0) cs   = 0.0;
      if (ssim < 0.0) ssim = 0.0;
      csAcc += cs; ssAcc += ssim;
    }
    csS[t] = (float)csAcc;
    ssS[t] = (float)ssAcc;
  }
  __syncthreads();

  if (t < B_*S_) {  // t = b*S_ + s
    double cb = 0.0, sb = 0.0;
    for (int m = 0; m < M_; ++m) { cb += (double)csS[t*M_ + m]; sb += (double)ssS[t*M_ + m]; }
    csb[t] = cb / (double)(M_*C_);
    ssb[t] = sb / (double)(M_*C_);
  }
  __syncthreads();

  if (t == 0) {
    double acc = 0.0;
    for (int b = 0; b < B_; ++b) {
      double p = ssb[b*S_ + (S_-1)];
      for (int s = 0; s < S_-1; ++s) p *= csb[b*S_ + s];
      acc += p;
    }
    out[0] = (float)(acc / (double)B_);
  }
}

extern "C" void kernel_launch(void* const* d_in, const int* in_sizes, int n_in,
                              void* d_out, int out_size, void* d_ws, size_t ws_size,
                              hipStream_t stream) {
  (void)in_sizes; (void)n_in; (void)out_size; (void)ws_size;
  const float4* X  = (const float4*)d_in[0];
  const float4* Y  = (const float4*)d_in[1];
  const float4* Mk = (const float4*)d_in[2];
  float* part = (float*)d_ws;        // NPLANE*SPLIT*16 floats = 507 KB
  float* out  = (float*)d_out;

  hipLaunchKernelGGL(moments_kernel, dim3(NBLK), dim3(TPB), 0, stream,
                     X, Y, Mk, part);
  hipLaunchKernelGGL(finalize_kernel, dim3(1), dim3(384), 0, stream, part, out);
}